// Round 8
// baseline (607.591 us; speedup 1.0000x reference)
//
#include <hip/hip_runtime.h>
#include <cstddef>
#include <cstdint>

// Problem constants
#define Bsz 8
#define Sseq 1024
#define Dm 1024
#define Hh 16
#define DH 64
#define DFF 2048
#define ROWS (Bsz*Sseq)            // 8192
#define EIGHT_M (8u*1024u*1024u)   // 8388608

#define QSCALE 0.180336880f        // 0.125 * log2(e) — folds softmax base-2

typedef _Float16 f16;
typedef _Float16 f16x8 __attribute__((ext_vector_type(8)));
typedef _Float16 f16x4 __attribute__((ext_vector_type(4)));
typedef float    f32x4 __attribute__((ext_vector_type(4)));

#define MFMA16(a,b,c) __builtin_amdgcn_mfma_f32_16x16x32_f16(a, b, c, 0, 0, 0)

// global->LDS direct copy, 16B per lane. LDS dst wave-uniform base; HW writes
// dst + lane*16. Global src per-lane.
__device__ __forceinline__ void glds16(const void* g, void* l) {
    __builtin_amdgcn_global_load_lds(
        (const __attribute__((address_space(1))) unsigned int*)g,
        (__attribute__((address_space(3))) unsigned int*)l, 16, 0, 0);
}

// ---------------------------------------------------------------------------
// LayerNorm (fp32 in, f16 out). One block per row of 1024.
// ---------------------------------------------------------------------------
__global__ __launch_bounds__(256) void ln_k(const float* __restrict__ x,
                                            const float* __restrict__ gain,
                                            const float* __restrict__ beta,
                                            f16* __restrict__ y)
{
    int row = blockIdx.x;
    const float* xr = x + (size_t)row * Dm;
    int tid = threadIdx.x;

    float4 v = *(const float4*)&xr[tid * 4];
    float s  = v.x + v.y + v.z + v.w;
    float sq = v.x*v.x + v.y*v.y + v.z*v.z + v.w*v.w;

    #pragma unroll
    for (int off = 32; off > 0; off >>= 1) {
        s  += __shfl_down(s,  off);
        sq += __shfl_down(sq, off);
    }
    __shared__ float ss[4], ssq[4];
    int w = tid >> 6, ln = tid & 63;
    if (ln == 0) { ss[w] = s; ssq[w] = sq; }
    __syncthreads();
    float S  = ss[0] + ss[1] + ss[2] + ss[3];
    float SQ = ssq[0] + ssq[1] + ssq[2] + ssq[3];

    float mean = S * (1.0f / 1024.0f);
    float var  = (SQ - 1024.0f * mean * mean) * (1.0f / 1023.0f);
    var = fmaxf(var, 0.0f);
    float inv = 1.0f / (sqrtf(var) + 1e-6f);

    float4 gv = *(const float4*)&gain[tid * 4];
    float4 bv = *(const float4*)&beta[tid * 4];
    f16x4 o;
    o[0] = (f16)(gv.x * inv * (v.x - mean) + bv.x);
    o[1] = (f16)(gv.y * inv * (v.y - mean) + bv.y);
    o[2] = (f16)(gv.z * inv * (v.z - mean) + bv.z);
    o[3] = (f16)(gv.w * inv * (v.w - mean) + bv.w);
    *(f16x4*)&y[(size_t)row * Dm + tid * 4] = o;
}

// ---------------------------------------------------------------------------
// Weight transpose+cast+scale: src fp32 [K][N] -> dst f16 [N][K]
// ---------------------------------------------------------------------------
__global__ __launch_bounds__(256) void transcast_k(const float* __restrict__ src,
                                                   f16* __restrict__ dst,
                                                   int K, int N, float scale)
{
    __shared__ float t[32][33];
    int n0 = blockIdx.x * 32, k0 = blockIdx.y * 32;
    int tx = threadIdx.x & 31, ty = threadIdx.x >> 5;   // ty 0..7
    #pragma unroll
    for (int i = 0; i < 4; ++i)
        t[ty + 8*i][tx] = src[(size_t)(k0 + ty + 8*i) * N + n0 + tx];
    __syncthreads();
    #pragma unroll
    for (int i = 0; i < 4; ++i)
        dst[(size_t)(n0 + ty + 8*i) * K + k0 + tx] = (f16)(t[tx][ty + 8*i] * scale);
}

// ---------------------------------------------------------------------------
// Bias concat: bcat[0:1024)=bq*QSCALE, [1024:2048)=bk, [2048:3072)=bv
// ---------------------------------------------------------------------------
__global__ __launch_bounds__(256) void biascat_k(const float* __restrict__ bq,
                                                 const float* __restrict__ bk,
                                                 const float* __restrict__ bv,
                                                 float* __restrict__ bcat)
{
    int i = blockIdx.x * 256 + threadIdx.x;   // 0..3071
    float v;
    if (i < 1024)       v = bq[i] * QSCALE;
    else if (i < 2048)  v = bk[i - 1024];
    else                v = bv[i - 2048];
    bcat[i] = v;
}

// ---------------------------------------------------------------------------
// V head-layout [bh][s][d] -> V^T [bh][d][s]  (f16)
// ---------------------------------------------------------------------------
__global__ __launch_bounds__(256) void vtrans_k(const f16* __restrict__ v,
                                                f16* __restrict__ vt)
{
    int bh = blockIdx.y;
    int s0 = blockIdx.x * 64;
    __shared__ f16 t[64][72];
    int tid = threadIdx.x;
    int sl = tid >> 2, dq = (tid & 3) * 16;
    const f16* src = v + ((size_t)bh * Sseq + s0 + sl) * DH + dq;
    *(f16x8*)&t[sl][dq]     = *(const f16x8*)&src[0];
    *(f16x8*)&t[sl][dq + 8] = *(const f16x8*)&src[8];
    __syncthreads();
    int d = tid >> 2, sq = (tid & 3) * 16;
    f16 buf[16];
    #pragma unroll
    for (int i = 0; i < 16; ++i) buf[i] = t[sq + i][d];
    f16* dst = vt + ((size_t)bh * DH + d) * Sseq + s0 + sq;
    *(f16x8*)&dst[0] = *(f16x8*)&buf[0];
    *(f16x8*)&dst[8] = *(f16x8*)&buf[8];
}

// ---------------------------------------------------------------------------
// f16 MFMA GEMM, k-half-rotation pipeline (T3+T4 counted vmcnt, T5 setprio):
//   BM=256, BN=128, BK=64, 512 threads (8 waves, 2M x 4N), per-wave C 128x32.
//   LDS single buffer, two k-half slots: As[2][16KB], Bs[2][8KB] = 48KB.
//   Chunk layout (16B units), u-major: A slot chunk = u*256+m, B = u*128+n
//   -> quarter-wave ds_read_b128 fragments are CONSECUTIVE chunks (256B
//      contiguous per 16 lanes = conflict-free)
//   -> glds dest stays linear (wave base + lane*16): rule-21 by construction.
//   Schedule per tile t: phase0(slot0) | bar | stage slot0<-t+1 | vmcnt(3) |
//   bar | phase1(slot1) | bar | stage slot1<-t+1 | vmcnt(3) | bar.
//   vmcnt(0) only on the last tile.
// EPI 0: fused QKV -> head-layout f16 (C0/C1/C2 by n0>>10)
// EPI 1: fp32 out + fp32 residual
// EPI 2: relu -> f16 row-major
// ---------------------------------------------------------------------------
template<int EPI>
__global__ __launch_bounds__(512) void gemm3_k(const f16* __restrict__ A,
                                               const f16* __restrict__ Bt,
                                               const float* __restrict__ bias,
                                               void* __restrict__ C0,
                                               void* __restrict__ C1,
                                               void* __restrict__ C2,
                                               const float* __restrict__ res,
                                               int M, int N, int K)
{
    __shared__ f16 As[2][8192];   // [khalf][1024 chunks * 8 f16]
    __shared__ f16 Bs[2][4096];   // [khalf][512 chunks * 8 f16]

    const int tid  = threadIdx.x;
    const int lane = tid & 63, w = tid >> 6;     // 8 waves
    const int wr = w >> 2, wc = w & 3;           // 2M x 4N
    const int lr = lane & 15, lg = lane >> 4;
    const int m0 = blockIdx.y * 256, n0 = blockIdx.x * 128;

    // staging sources: A chunks c = w*128 + {0,64} + lane  (u = c>>8, m = c&255)
    //                  B chunks c = w*64 + lane            (u = c>>7, n = c&127)
    const int cA0 = w * 128 + lane;
    const int cA1 = cA0 + 64;
    const int cB  = w * 64 + lane;
    const f16* srcA0 = A  + (size_t)(m0 + (cA0 & 255)) * K + (cA0 >> 8) * 8;
    const f16* srcA1 = A  + (size_t)(m0 + (cA1 & 255)) * K + (cA1 >> 8) * 8;
    const f16* srcB  = Bt + (size_t)(n0 + (cB  & 127)) * K + (cB  >> 7) * 8;

    f32x4 acc[8][2];
    #pragma unroll
    for (int i = 0; i < 8; ++i) {
        acc[i][0] = (f32x4){0.f, 0.f, 0.f, 0.f};
        acc[i][1] = (f32x4){0.f, 0.f, 0.f, 0.f};
    }

    int aoffs[8], boffs[2];
    #pragma unroll
    for (int mi = 0; mi < 8; ++mi)
        aoffs[mi] = (lg * 256 + wr * 128 + mi * 16 + lr) * 8;
    #pragma unroll
    for (int ni = 0; ni < 2; ++ni)
        boffs[ni] = (lg * 128 + wc * 32 + ni * 16 + lr) * 8;

    #define STAGE(h, koff) do {                                          \
        glds16(srcA0 + (koff) + (h) * 32, &As[h][w * 1024]);             \
        glds16(srcA1 + (koff) + (h) * 32, &As[h][w * 1024 + 512]);       \
        glds16(srcB  + (koff) + (h) * 32, &Bs[h][w * 512]);              \
    } while (0)

    #define PHASE(ks) do {                                               \
        f16x8 af[8], bf[2];                                              \
        _Pragma("unroll")                                                \
        for (int mi = 0; mi < 8; ++mi)                                   \
            af[mi] = *(const f16x8*)&As[ks][aoffs[mi]];                  \
        _Pragma("unroll")                                                \
        for (int ni = 0; ni < 2; ++ni)                                   \
            bf[ni] = *(const f16x8*)&Bs[ks][boffs[ni]];                  \
        __builtin_amdgcn_s_setprio(1);                                   \
        _Pragma("unroll")                                                \
        for (int mi = 0; mi < 8; ++mi) {                                 \
            acc[mi][0] = MFMA16(af[mi], bf[0], acc[mi][0]);              \
            acc[mi][1] = MFMA16(af[mi], bf[1], acc[mi][1]);              \
        }                                                                \
        __builtin_amdgcn_s_setprio(0);                                   \
    } while (0)

    #define FENCE() asm volatile("" ::: "memory")

    // prologue: stage both k-halves of tile 0
    STAGE(0, 0);
    STAGE(1, 0);
    asm volatile("s_waitcnt vmcnt(3)" ::: "memory");   // slot0 landed
    __builtin_amdgcn_s_barrier();
    FENCE();

    const int NT = K >> 6;
    for (int t = 0; t < NT; ++t) {
        const bool lastt = (t == NT - 1);

        PHASE(0);
        FENCE();
        __builtin_amdgcn_s_barrier();      // all waves done reading slot0
        FENCE();
        if (!lastt) {
            STAGE(0, (t + 1) * 64);
            asm volatile("s_waitcnt vmcnt(3)" ::: "memory");  // slot1(t) landed
        } else {
            asm volatile("s_waitcnt vmcnt(0)" ::: "memory");
        }
        __builtin_amdgcn_s_barrier();      // slot1(t) visible to all waves
        FENCE();

        PHASE(1);
        FENCE();
        __builtin_amdgcn_s_barrier();      // all waves done reading slot1
        FENCE();
        if (!lastt) {
            STAGE(1, (t + 1) * 64);
            asm volatile("s_waitcnt vmcnt(3)" ::: "memory");  // slot0(t+1) landed
            __builtin_amdgcn_s_barrier();  // slot0(t+1) visible
            FENCE();
        }
    }
    #undef STAGE
    #undef PHASE
    #undef FENCE

    // epilogue: lane holds C[row=lg*4+r][col=lr] per 16x16 frag
    if constexpr (EPI == 0) {
        int seg = n0 >> 10;                 // uniform per block
        f16* dst = (seg == 0) ? (f16*)C0 : ((seg == 1) ? (f16*)C1 : (f16*)C2);
        int nn0 = n0 & 1023;
        #pragma unroll
        for (int mi = 0; mi < 8; ++mi)
            #pragma unroll
            for (int r = 0; r < 4; ++r) {
                int gm = m0 + wr * 128 + mi * 16 + lg * 4 + r;
                int b = gm >> 10, s = gm & 1023;
                #pragma unroll
                for (int ni = 0; ni < 2; ++ni) {
                    int n = nn0 + wc * 32 + ni * 16 + lr;
                    int h = n >> 6, d = n & 63;
                    float v = acc[mi][ni][r] + bias[n0 + wc * 32 + ni * 16 + lr];
                    dst[(((size_t)(b * 16 + h) * 1024 + s) << 6) + d] = (f16)v;
                }
            }
    } else {
        #pragma unroll
        for (int mi = 0; mi < 8; ++mi)
            #pragma unroll
            for (int r = 0; r < 4; ++r) {
                int gm = m0 + wr * 128 + mi * 16 + lg * 4 + r;
                #pragma unroll
                for (int ni = 0; ni < 2; ++ni) {
                    int gn = n0 + wc * 32 + ni * 16 + lr;
                    float v = acc[mi][ni][r] + bias[gn];
                    if constexpr (EPI == 1) {
                        ((float*)C0)[(size_t)gm * N + gn] =
                            v + res[(size_t)gm * N + gn];
                    } else {
                        ((f16*)C0)[(size_t)gm * N + gn] = (f16)fmaxf(v, 0.f);
                    }
                }
            }
    }
}

// ---------------------------------------------------------------------------
// MFMA flash attention with SWAPPED QK^T -> lane-local softmax (T12 core).
// Block = 64 q-rows x (b,h). 4 waves; wave w owns q rows [w*16, w*16+16).
// A/B fragment layouts are identical for 16x16x32, so MFMA16(kf, qf) computes
// S^T with unchanged K/Q loads: lane (lg,lr) then holds 16 scores for the
// SINGLE q-row q=w*16+lr at kv = ni*16+lg*4+r. Row-reduce = 15 lane-local ops
// + 2 shfl_xor(16,32) across the 4 redundant lanes. P written back to the
// same Ps[q][kv] layout, so PV / accumulator / output are unchanged.
// Per-q-row factors for oacc (rows q=lg*4+r) fetched via __shfl from lane
// lg*4+r (its lr == that row). Q pre-scaled by 0.125*log2e -> exp2 softmax.
// ---------------------------------------------------------------------------
__global__ __launch_bounds__(256) void attn_k(const f16* __restrict__ q,
                                              const f16* __restrict__ k,
                                              const f16* __restrict__ vt,
                                              const int* __restrict__ mask,
                                              f16* __restrict__ o)
{
    int bh = blockIdx.y;          // 0..127
    int b  = bh >> 4, h = bh & 15;
    int q0 = blockIdx.x * 64;

    const f16* Qb = q  + (size_t)bh * (Sseq * DH);   // [s][d]
    const f16* Kb = k  + (size_t)bh * (Sseq * DH);   // [s][d]
    const f16* Vb = vt + (size_t)bh * (DH * Sseq);   // [d][s]

    __shared__ f16 Ks[64 * 64];      // [kv][d] swizzled
    __shared__ f16 Vts[64 * 64];     // [d][kv] swizzled
    __shared__ f16 Ps[4][16][72];    // per-wave P[q within tile][kv], padded

    int tid  = threadIdx.x;
    int lane = tid & 63, w = tid >> 6;
    int lr = lane & 15, lg = lane >> 4;

    f16x8 qf[2];
    {
        const f16* qr = Qb + (size_t)(q0 + w * 16 + lr) * DH + lg * 8;
        qf[0] = *(const f16x8*)&qr[0];
        qf[1] = *(const f16x8*)&qr[32];
    }

    f32x4 oacc[4];
    #pragma unroll
    for (int ni = 0; ni < 4; ++ni) oacc[ni] = (f32x4){0.f, 0.f, 0.f, 0.f};
    float m_i = -1e30f, l_i = 0.f;        // state for q = w*16 + lr

    int srow8 = lane >> 3;        // 0..7 row-in-chunk
    int sc16  = lane & 7;         // 16B unit in row

    for (int t0 = 0; t0 < Sseq; t0 += 64) {
        #pragma unroll
        for (int c = 0; c < 2; ++c) {
            int ch  = 2 * w + c;
            int row = ch * 8 + srow8;
            int cs  = sc16 ^ (row & 7);   // inverse-swizzled source unit
            glds16(Kb + (size_t)(t0 + row) * DH + cs * 8,  Ks  + ch * 512);
            glds16(Vb + (size_t)row * Sseq + t0 + cs * 8,  Vts + ch * 512);
        }
        __syncthreads();

        // S^T = K @ Q^T : s2[ni][r] = S[q=w*16+lr][kv=t0+ni*16+lg*4+r]
        f32x4 s2[4];
        #pragma unroll
        for (int ni = 0; ni < 4; ++ni) s2[ni] = (f32x4){0.f, 0.f, 0.f, 0.f};
        #pragma unroll
        for (int ks = 0; ks < 2; ++ks) {
            #pragma unroll
            for (int ni = 0; ni < 4; ++ni) {
                int row = ni * 16 + lr;
                f16x8 kf = *(const f16x8*)
                    &Ks[row * 64 + ((((ks << 2) | lg) ^ (row & 7)) << 3)];
                s2[ni] = MFMA16(kf, qf[ks], s2[ni]);
            }
        }

        // mask (per kv = ni*16 + lg*4 + r)
        const int* mrow = mask + b * Sseq + t0;
        #pragma unroll
        for (int ni = 0; ni < 4; ++ni) {
            int4 mv = *(const int4*)&mrow[ni * 16 + lg * 4];
            if (mv.x == 0) s2[ni][0] = -1e9f;
            if (mv.y == 0) s2[ni][1] = -1e9f;
            if (mv.z == 0) s2[ni][2] = -1e9f;
            if (mv.w == 0) s2[ni][3] = -1e9f;
        }

        // row max: 16 lane-local values + 2 shfl_xor across redundant lanes
        float pmax = fmaxf(fmaxf(s2[0][0], s2[0][1]), fmaxf(s2[0][2], s2[0][3]));
        #pragma unroll
        for (int ni = 1; ni < 4; ++ni)
            pmax = fmaxf(pmax,
                   fmaxf(fmaxf(s2[ni][0], s2[ni][1]), fmaxf(s2[ni][2], s2[ni][3])));
        pmax = fmaxf(pmax, __shfl_xor(pmax, 16));
        pmax = fmaxf(pmax, __shfl_xor(pmax, 32));

        // T13 defer-max: rescale only when max grew by > 8 (log2 units)
        if (__any(pmax > m_i + 8.0f)) {
            float mnew = fmaxf(m_i, pmax);
            float al = exp2f(m_i - mnew);     // for q = w*16 + lr
            m_i = mnew;
            l_i *= al;
            // fetch alpha for oacc rows q = w*16 + lg*4 + r (lane lg*4+r has it)
            #pragma unroll
            for (int r = 0; r < 4; ++r) {
                float alr = __shfl(al, lg * 4 + r);
                #pragma unroll
                for (int ni = 0; ni < 4; ++ni) oacc[ni][r] *= alr;
            }
        }

        // p = exp2(s - m), bounded by 2^8; write back to Ps[q][kv]
        float rsum = 0.f;
        #pragma unroll
        for (int ni = 0; ni < 4; ++ni) {
            #pragma unroll
            for (int r = 0; r < 4; ++r) {
                float p = exp2f(s2[ni][r] - m_i);
                Ps[w][lr][ni * 16 + lg * 4 + r] = (f16)p;
                rsum += p;
            }
        }
        rsum += __shfl_xor(rsum, 16);
        rsum += __shfl_xor(rsum, 32);
        l_i += rsum;

        // PV: O += P @ V  (unchanged: A-frag row=lr from Ps, B-frag from Vts)
        #pragma unroll
        for (int ks = 0; ks < 2; ++ks) {
            f16x8 pf = *(const f16x8*)&Ps[w][lr][ks * 32 + lg * 8];
            #pragma unroll
            for (int ni = 0; ni < 4; ++ni) {
                int row = ni * 16 + lr;
                f16x8 vf = *(const f16x8*)
                    &Vts[row * 64 + ((((ks << 2) | lg) ^ (row & 7)) << 3)];
                oacc[ni] = MFMA16(pf, vf, oacc[ni]);
            }
        }
        __syncthreads();
    }

    // normalize (1/l for rows q=lg*4+r fetched from lane lg*4+r), store
    float invl = 1.0f / l_i;
    size_t rbase = (size_t)b * Sseq + q0 + w * 16;
    #pragma unroll
    for (int r = 0; r < 4; ++r) {
        float invr = __shfl(invl, lg * 4 + r);
        #pragma unroll
        for (int ni = 0; ni < 4; ++ni)
            o[(rbase + lg * 4 + r) * Dm + h * 64 + ni * 16 + lr] =
                (f16)(oacc[ni][r] * invr);
    }
}

// ---------------------------------------------------------------------------
// Buffer plan (ws = 32M f16 = 64MB; d_out doubles as scratch):
//   ws f16 [0,3M):    wcatT (wq*QS | wk | wv, each [1024][1024])
//   ws f16 [3M,4M):   woT
//   ws f16 [4M,6M):   w1T   [2048][1024]
//   ws f16 [6M,8M):   w2T   [1024][2048]
//   ws f16 [8M,16M):  xn -> ob -> an
//   ws f16 [16M,32M): qh,kh -> h1
//   d_out out-half:   vh (8M f16) + vth (8M f16) -> final out (fp32)
//   d_out attn-half:  bcat fp32[3072] (dead at step 5) -> attn (output #2)
// ---------------------------------------------------------------------------
extern "C" void kernel_launch(void* const* d_in, const int* in_sizes, int n_in,
                              void* d_out, int out_size, void* d_ws, size_t ws_size,
                              hipStream_t stream)
{
    const float* x     = (const float*)d_in[0];
    const int*   mask  = (const int*)  d_in[1];
    const float* wq    = (const float*)d_in[2];
    const float* bq    = (const float*)d_in[3];
    const float* wk    = (const float*)d_in[4];
    const float* bk    = (const float*)d_in[5];
    const float* wv    = (const float*)d_in[6];
    const float* bv    = (const float*)d_in[7];
    const float* wo    = (const float*)d_in[8];
    const float* bo    = (const float*)d_in[9];
    const float* w1    = (const float*)d_in[10];
    const float* b1    = (const float*)d_in[11];
    const float* w2    = (const float*)d_in[12];
    const float* b2    = (const float*)d_in[13];
    const float* g1    = (const float*)d_in[14];
    const float* beta1 = (const float*)d_in[15];
    const float* g2    = (const float*)d_in[16];
    const float* beta2 = (const float*)d_in[17];

    float* out  = (float*)d_out;
    float* attn = out + EIGHT_M;

    const size_t M1 = 1024 * 1024;
    f16* ws16 = (f16*)d_ws;
    f16* wcatT = ws16;               // 3M
    f16* woT   = ws16 + 3 * M1;
    f16* w1T   = ws16 + 4 * M1;      // [2048][1024]
    f16* w2T   = ws16 + 6 * M1;      // [1024][2048]
    f16* xn    = ws16 + 8 * M1;      // 8M
    f16* ob    = xn;                 // alias (xn dead after QKV)
    f16* an    = xn;                 // alias (ob dead after O-proj)
    f16* qh    = ws16 + 16 * M1;     // 8M
    f16* kh    = ws16 + 24 * M1;     // 8M
    f16* h1    = qh;                 // 16M (q,k dead)
    f16* vh    = (f16*)d_out;        // out-half scratch
    f16* vth   = vh + 8 * M1;
    float* bcat = attn;              // 3072 fp32, dead before attn written

    dim3 tb256(256), tb512(512);

    // 0. weight prep
    transcast_k<<<dim3(32, 32), tb256, 0, stream>>>(wq, wcatT,          1024, 1024, QSCALE);
    transcast_k<<<dim3(32, 32), tb256, 0, stream>>>(wk, wcatT + 1 * M1, 1024, 1024, 1.0f);
    transcast_k<<<dim3(32, 32), tb256, 0, stream>>>(wv, wcatT + 2 * M1, 1024, 1024, 1.0f);
    transcast_k<<<dim3(32, 32), tb256, 0, stream>>>(wo, woT,            1024, 1024, 1.0f);
    transcast_k<<<dim3(64, 32), tb256, 0, stream>>>(w1, w1T,            1024, 2048, 1.0f);
    transcast_k<<<dim3(32, 64), tb256, 0, stream>>>(w2, w2T,            2048, 1024, 1.0f);
    biascat_k<<<12, tb256, 0, stream>>>(bq, bk, bv, bcat);

    // 1. LN1
    ln_k<<<ROWS, tb256, 0, stream>>>(x, g1, beta1, xn);

    // 2. fused QKV projection (head layout f16; Q pre-scaled by QSCALE)
    gemm3_k<0><<<dim3(3072 / 128, ROWS / 256), tb512, 0, stream>>>(
        xn, wcatT, bcat, qh, kh, vh, nullptr, ROWS, 3072, Dm);

    // 3. V -> V^T per head
    vtrans_k<<<dim3(16, 128), tb256, 0, stream>>>(vh, vth);

    // 4. flash attention -> ob row-major f16
    attn_k<<<dim3(16, 128), tb256, 0, stream>>>(qh, kh, vth, mask, ob);

    // 5. O projection + residual -> attn (fp32, output #2)
    gemm3_k<1><<<dim3(1024 / 128, ROWS / 256), tb512, 0, stream>>>(
        ob, woT, bo, attn, nullptr, nullptr, x, ROWS, Dm, Dm);

    // 6. LN2 -> an f16
    ln_k<<<ROWS, tb256, 0, stream>>>(attn, g2, beta2, an);

    // 7. FFN1: relu(an @ w1 + b1) -> h1 f16
    gemm3_k<2><<<dim3(2048 / 128, ROWS / 256), tb512, 0, stream>>>(
        an, w1T, b1, h1, nullptr, nullptr, nullptr, ROWS, DFF, Dm);

    // 8. FFN2: attn + h1 @ w2 + b2 -> out (fp32, output #1)
    gemm3_k<1><<<dim3(1024 / 128, ROWS / 256), tb512, 0, stream>>>(
        h1, w2T, b2, out, nullptr, nullptr, attn, ROWS, Dm, DFF);
}

// Round 12
// 563.364 us; speedup vs baseline: 1.0785x; 1.0785x over previous
//
#include <hip/hip_runtime.h>
#include <cstddef>
#include <cstdint>

// Problem constants
#define Bsz 8
#define Sseq 1024
#define Dm 1024
#define Hh 16
#define DH 64
#define DFF 2048
#define ROWS (Bsz*Sseq)            // 8192
#define EIGHT_M (8u*1024u*1024u)   // 8388608

#define QSCALE 0.180336880f        // 0.125 * log2(e) — folds softmax base-2

typedef _Float16 f16;
typedef _Float16 f16x8 __attribute__((ext_vector_type(8)));
typedef _Float16 f16x4 __attribute__((ext_vector_type(4)));
typedef float    f32x4 __attribute__((ext_vector_type(4)));

#define MFMA16(a,b,c) __builtin_amdgcn_mfma_f32_16x16x32_f16(a, b, c, 0, 0, 0)

// global->LDS direct copy, 16B per lane. LDS dst wave-uniform base; HW writes
// dst + lane*16. Global src per-lane.
__device__ __forceinline__ void glds16(const void* g, void* l) {
    __builtin_amdgcn_global_load_lds(
        (const __attribute__((address_space(1))) unsigned int*)g,
        (__attribute__((address_space(3))) unsigned int*)l, 16, 0, 0);
}

// ---------------------------------------------------------------------------
// LayerNorm (fp32 in, f16 out). One block per row of 1024.
// ---------------------------------------------------------------------------
__global__ __launch_bounds__(256) void ln_k(const float* __restrict__ x,
                                            const float* __restrict__ gain,
                                            const float* __restrict__ beta,
                                            f16* __restrict__ y)
{
    int row = blockIdx.x;
    const float* xr = x + (size_t)row * Dm;
    int tid = threadIdx.x;

    float4 v = *(const float4*)&xr[tid * 4];
    float s  = v.x + v.y + v.z + v.w;
    float sq = v.x*v.x + v.y*v.y + v.z*v.z + v.w*v.w;

    #pragma unroll
    for (int off = 32; off > 0; off >>= 1) {
        s  += __shfl_down(s,  off);
        sq += __shfl_down(sq, off);
    }
    __shared__ float ss[4], ssq[4];
    int w = tid >> 6, ln = tid & 63;
    if (ln == 0) { ss[w] = s; ssq[w] = sq; }
    __syncthreads();
    float S  = ss[0] + ss[1] + ss[2] + ss[3];
    float SQ = ssq[0] + ssq[1] + ssq[2] + ssq[3];

    float mean = S * (1.0f / 1024.0f);
    float var  = (SQ - 1024.0f * mean * mean) * (1.0f / 1023.0f);
    var = fmaxf(var, 0.0f);
    float inv = 1.0f / (sqrtf(var) + 1e-6f);

    float4 gv = *(const float4*)&gain[tid * 4];
    float4 bv = *(const float4*)&beta[tid * 4];
    f16x4 o;
    o[0] = (f16)(gv.x * inv * (v.x - mean) + bv.x);
    o[1] = (f16)(gv.y * inv * (v.y - mean) + bv.y);
    o[2] = (f16)(gv.z * inv * (v.z - mean) + bv.z);
    o[3] = (f16)(gv.w * inv * (v.w - mean) + bv.w);
    *(f16x4*)&y[(size_t)row * Dm + tid * 4] = o;
}

// ---------------------------------------------------------------------------
// Weight transpose+cast+scale: src fp32 [K][N] -> dst f16 [N][K]
// ---------------------------------------------------------------------------
__global__ __launch_bounds__(256) void transcast_k(const float* __restrict__ src,
                                                   f16* __restrict__ dst,
                                                   int K, int N, float scale)
{
    __shared__ float t[32][33];
    int n0 = blockIdx.x * 32, k0 = blockIdx.y * 32;
    int tx = threadIdx.x & 31, ty = threadIdx.x >> 5;   // ty 0..7
    #pragma unroll
    for (int i = 0; i < 4; ++i)
        t[ty + 8*i][tx] = src[(size_t)(k0 + ty + 8*i) * N + n0 + tx];
    __syncthreads();
    #pragma unroll
    for (int i = 0; i < 4; ++i)
        dst[(size_t)(n0 + ty + 8*i) * K + k0 + tx] = (f16)(t[tx][ty + 8*i] * scale);
}

// ---------------------------------------------------------------------------
// Bias concat: bcat[0:1024)=bq*QSCALE, [1024:2048)=bk, [2048:3072)=bv
// ---------------------------------------------------------------------------
__global__ __launch_bounds__(256) void biascat_k(const float* __restrict__ bq,
                                                 const float* __restrict__ bk,
                                                 const float* __restrict__ bv,
                                                 float* __restrict__ bcat)
{
    int i = blockIdx.x * 256 + threadIdx.x;   // 0..3071
    float v;
    if (i < 1024)       v = bq[i] * QSCALE;
    else if (i < 2048)  v = bk[i - 1024];
    else                v = bv[i - 2048];
    bcat[i] = v;
}

// ---------------------------------------------------------------------------
// V head-layout [bh][s][d] -> V^T [bh][d][s]  (f16)
// ---------------------------------------------------------------------------
__global__ __launch_bounds__(256) void vtrans_k(const f16* __restrict__ v,
                                                f16* __restrict__ vt)
{
    int bh = blockIdx.y;
    int s0 = blockIdx.x * 64;
    __shared__ f16 t[64][72];
    int tid = threadIdx.x;
    int sl = tid >> 2, dq = (tid & 3) * 16;
    const f16* src = v + ((size_t)bh * Sseq + s0 + sl) * DH + dq;
    *(f16x8*)&t[sl][dq]     = *(const f16x8*)&src[0];
    *(f16x8*)&t[sl][dq + 8] = *(const f16x8*)&src[8];
    __syncthreads();
    int d = tid >> 2, sq = (tid & 3) * 16;
    f16 buf[16];
    #pragma unroll
    for (int i = 0; i < 16; ++i) buf[i] = t[sq + i][d];
    f16* dst = vt + ((size_t)bh * DH + d) * Sseq + s0 + sq;
    *(f16x8*)&dst[0] = *(f16x8*)&buf[0];
    *(f16x8*)&dst[8] = *(f16x8*)&buf[8];
}

// ---------------------------------------------------------------------------
// gemm4: f16 MFMA GEMM with 3-slot ring + full-tile prefetch depth (T3/T4/T5).
//   BM=BN=128, BK=64 (k-halves of 32), 256 threads = 4 waves (2M x 2N),
//   per-wave C = 64x64 (4x4 frags), A-frags register-reused across both
//   B-half sub-phases -> 16KB LDS-read per wave per K-tile for 32 MFMA.
//   LDS: As[3][4096] + Bs[3][4096] f16 = 48KB; slot = half-index hh mod 3.
//   u-major chunk layout (chunk c = u*128 + row, addr = c*16B):
//     quarter-wave ds_read_b128 = 256B contiguous -> conflict-free (R8: 0)
//     glds dest linear (wave base + lane*16) -> rule-21 by construction.
//   Per half hh: vmcnt(4) [retire slot-hh's own 4 loads; slot-(hh+1)'s stay
//   in flight] -> barrier -> STAGE slot hh+2 (after barrier = overwrite-safe;
//   waves' ds_reads of that slot completed before they passed the barrier)
//   -> ds_read A(4)+B(2), 8 MFMA, ds_read B(2), 8 MFMA.
//   Prefetch distance = 2 halves (~4 sub-phases); vmcnt(0) only at last half.
// EPI 0: fused QKV -> head-layout f16 (C0/C1/C2 by n0>>10)
// EPI 1: fp32 out + fp32 residual
// EPI 2: relu -> f16 row-major
// ---------------------------------------------------------------------------
template<int EPI>
__global__ __launch_bounds__(256) void gemm4_k(const f16* __restrict__ A,
                                               const f16* __restrict__ Bt,
                                               const float* __restrict__ bias,
                                               void* __restrict__ C0,
                                               void* __restrict__ C1,
                                               void* __restrict__ C2,
                                               const float* __restrict__ res,
                                               int M, int N, int K)
{
    __shared__ f16 As[3][4096];   // [slot][512 chunks * 8 f16] = 8KB/slot
    __shared__ f16 Bs[3][4096];

    const int tid  = threadIdx.x;
    const int lane = tid & 63, w = tid >> 6;     // 4 waves
    const int wr = w >> 1, wc = w & 1;           // 2M x 2N
    const int lr = lane & 15, lg = lane >> 4;
    const int m0 = blockIdx.y * 128, n0 = blockIdx.x * 128;

    // staging: 512 chunks per slot; rounds r=0,1: chunk c = r*256 + w*64 + lane
    // chunk c -> row (c&127), u (c>>7); src elem = row*K + kbase + u*8
    const int c0 = w * 64 + lane;
    const int c1 = c0 + 256;
    const f16* srcA0 = A  + (size_t)(m0 + (c0 & 127)) * K + ((c0 >> 7) << 3);
    const f16* srcA1 = A  + (size_t)(m0 + (c1 & 127)) * K + ((c1 >> 7) << 3);
    const f16* srcB0 = Bt + (size_t)(n0 + (c0 & 127)) * K + ((c0 >> 7) << 3);
    const f16* srcB1 = Bt + (size_t)(n0 + (c1 & 127)) * K + ((c1 >> 7) << 3);
    const int dst0 = (w * 64) * 8;            // wave-uniform f16 offsets
    const int dst1 = (256 + w * 64) * 8;

    f32x4 acc[4][4];
    #pragma unroll
    for (int i = 0; i < 4; ++i)
        #pragma unroll
        for (int j = 0; j < 4; ++j)
            acc[i][j] = (f32x4){0.f, 0.f, 0.f, 0.f};

    int aoff[4], boff[4];
    #pragma unroll
    for (int mi = 0; mi < 4; ++mi)
        aoff[mi] = (lg * 128 + wr * 64 + mi * 16 + lr) * 8;
    #pragma unroll
    for (int nf = 0; nf < 4; ++nf)
        boff[nf] = (lg * 128 + wc * 64 + nf * 16 + lr) * 8;

    #define STAGE(sl_, kb_) do {                                         \
        glds16(srcA0 + (kb_), &As[sl_][dst0]);                           \
        glds16(srcA1 + (kb_), &As[sl_][dst1]);                           \
        glds16(srcB0 + (kb_), &Bs[sl_][dst0]);                           \
        glds16(srcB1 + (kb_), &Bs[sl_][dst1]);                           \
    } while (0)

    #define FENCE() asm volatile("" ::: "memory")

    // prologue: stage halves 0 and 1 into slots 0, 1  (8 loads in flight)
    STAGE(0, 0);
    STAGE(1, 32);
    FENCE();

    const int NH = K >> 5;      // number of 32-k halves (>= 32 here)
    int sl = 0;
    for (int hh = 0; hh < NH; ++hh) {
        // retire this slot's own 4 loads; keep next slot's 4 in flight
        if (hh < NH - 1) {
            asm volatile("s_waitcnt vmcnt(4)" ::: "memory");
        } else {
            asm volatile("s_waitcnt vmcnt(0)" ::: "memory");
        }
        __builtin_amdgcn_s_barrier();   // all waves' loads for slot sl landed;
        FENCE();                        // all waves done reading slot (hh+2)%3
        if (hh + 2 < NH) {
            int s2 = sl + 2; if (s2 >= 3) s2 -= 3;
            STAGE(s2, (hh + 2) * 32);
        }

        // sub-phase 0: A-frags (reused below) + B lower half
        f16x8 a0 = *(const f16x8*)&As[sl][aoff[0]];
        f16x8 a1 = *(const f16x8*)&As[sl][aoff[1]];
        f16x8 a2 = *(const f16x8*)&As[sl][aoff[2]];
        f16x8 a3 = *(const f16x8*)&As[sl][aoff[3]];
        f16x8 b0 = *(const f16x8*)&Bs[sl][boff[0]];
        f16x8 b1 = *(const f16x8*)&Bs[sl][boff[1]];
        __builtin_amdgcn_s_setprio(1);
        acc[0][0] = MFMA16(a0, b0, acc[0][0]);
        acc[0][1] = MFMA16(a0, b1, acc[0][1]);
        acc[1][0] = MFMA16(a1, b0, acc[1][0]);
        acc[1][1] = MFMA16(a1, b1, acc[1][1]);
        acc[2][0] = MFMA16(a2, b0, acc[2][0]);
        acc[2][1] = MFMA16(a2, b1, acc[2][1]);
        acc[3][0] = MFMA16(a3, b0, acc[3][0]);
        acc[3][1] = MFMA16(a3, b1, acc[3][1]);
        __builtin_amdgcn_s_setprio(0);

        // sub-phase 1: B upper half (A reused from registers)
        f16x8 b2 = *(const f16x8*)&Bs[sl][boff[2]];
        f16x8 b3 = *(const f16x8*)&Bs[sl][boff[3]];
        __builtin_amdgcn_s_setprio(1);
        acc[0][2] = MFMA16(a0, b2, acc[0][2]);
        acc[0][3] = MFMA16(a0, b3, acc[0][3]);
        acc[1][2] = MFMA16(a1, b2, acc[1][2]);
        acc[1][3] = MFMA16(a1, b3, acc[1][3]);
        acc[2][2] = MFMA16(a2, b2, acc[2][2]);
        acc[2][3] = MFMA16(a2, b3, acc[2][3]);
        acc[3][2] = MFMA16(a3, b2, acc[3][2]);
        acc[3][3] = MFMA16(a3, b3, acc[3][3]);
        __builtin_amdgcn_s_setprio(0);

        FENCE();
        sl = (sl + 1 == 3) ? 0 : sl + 1;
    }
    #undef STAGE
    #undef FENCE

    // epilogue: lane holds C[row = lg*4+r][col = lr] per 16x16 frag
    if constexpr (EPI == 0) {
        int seg = n0 >> 10;                 // uniform per block
        f16* dst = (seg == 0) ? (f16*)C0 : ((seg == 1) ? (f16*)C1 : (f16*)C2);
        int nn0 = n0 & 1023;
        #pragma unroll
        for (int mi = 0; mi < 4; ++mi)
            #pragma unroll
            for (int r = 0; r < 4; ++r) {
                int gm = m0 + wr * 64 + mi * 16 + lg * 4 + r;
                int b = gm >> 10, s = gm & 1023;
                #pragma unroll
                for (int nf = 0; nf < 4; ++nf) {
                    int n = nn0 + wc * 64 + nf * 16 + lr;
                    int h = n >> 6, d = n & 63;
                    float v = acc[mi][nf][r] + bias[n0 + wc * 64 + nf * 16 + lr];
                    dst[(((size_t)(b * 16 + h) * 1024 + s) << 6) + d] = (f16)v;
                }
            }
    } else {
        #pragma unroll
        for (int mi = 0; mi < 4; ++mi)
            #pragma unroll
            for (int r = 0; r < 4; ++r) {
                int gm = m0 + wr * 64 + mi * 16 + lg * 4 + r;
                #pragma unroll
                for (int nf = 0; nf < 4; ++nf) {
                    int gn = n0 + wc * 64 + nf * 16 + lr;
                    float v = acc[mi][nf][r] + bias[gn];
                    if constexpr (EPI == 1) {
                        ((float*)C0)[(size_t)gm * N + gn] =
                            v + res[(size_t)gm * N + gn];
                    } else {
                        ((f16*)C0)[(size_t)gm * N + gn] = (f16)fmaxf(v, 0.f);
                    }
                }
            }
    }
}

// ---------------------------------------------------------------------------
// MFMA flash attention with SWAPPED QK^T -> lane-local softmax (unchanged
// from round 8, which passed at absmax 0.03125).
// ---------------------------------------------------------------------------
__global__ __launch_bounds__(256) void attn_k(const f16* __restrict__ q,
                                              const f16* __restrict__ k,
                                              const f16* __restrict__ vt,
                                              const int* __restrict__ mask,
                                              f16* __restrict__ o)
{
    int bh = blockIdx.y;          // 0..127
    int b  = bh >> 4, h = bh & 15;
    int q0 = blockIdx.x * 64;

    const f16* Qb = q  + (size_t)bh * (Sseq * DH);   // [s][d]
    const f16* Kb = k  + (size_t)bh * (Sseq * DH);   // [s][d]
    const f16* Vb = vt + (size_t)bh * (DH * Sseq);   // [d][s]

    __shared__ f16 Ks[64 * 64];      // [kv][d] swizzled
    __shared__ f16 Vts[64 * 64];     // [d][kv] swizzled
    __shared__ f16 Ps[4][16][72];    // per-wave P[q within tile][kv], padded

    int tid  = threadIdx.x;
    int lane = tid & 63, w = tid >> 6;
    int lr = lane & 15, lg = lane >> 4;

    f16x8 qf[2];
    {
        const f16* qr = Qb + (size_t)(q0 + w * 16 + lr) * DH + lg * 8;
        qf[0] = *(const f16x8*)&qr[0];
        qf[1] = *(const f16x8*)&qr[32];
    }

    f32x4 oacc[4];
    #pragma unroll
    for (int ni = 0; ni < 4; ++ni) oacc[ni] = (f32x4){0.f, 0.f, 0.f, 0.f};
    float m_i = -1e30f, l_i = 0.f;        // state for q = w*16 + lr

    int srow8 = lane >> 3;        // 0..7 row-in-chunk
    int sc16  = lane & 7;         // 16B unit in row

    for (int t0 = 0; t0 < Sseq; t0 += 64) {
        #pragma unroll
        for (int c = 0; c < 2; ++c) {
            int ch  = 2 * w + c;
            int row = ch * 8 + srow8;
            int cs  = sc16 ^ (row & 7);   // inverse-swizzled source unit
            glds16(Kb + (size_t)(t0 + row) * DH + cs * 8,  Ks  + ch * 512);
            glds16(Vb + (size_t)row * Sseq + t0 + cs * 8,  Vts + ch * 512);
        }
        __syncthreads();

        // S^T = K @ Q^T : s2[ni][r] = S[q=w*16+lr][kv=t0+ni*16+lg*4+r]
        f32x4 s2[4];
        #pragma unroll
        for (int ni = 0; ni < 4; ++ni) s2[ni] = (f32x4){0.f, 0.f, 0.f, 0.f};
        #pragma unroll
        for (int ks = 0; ks < 2; ++ks) {
            #pragma unroll
            for (int ni = 0; ni < 4; ++ni) {
                int row = ni * 16 + lr;
                f16x8 kf = *(const f16x8*)
                    &Ks[row * 64 + ((((ks << 2) | lg) ^ (row & 7)) << 3)];
                s2[ni] = MFMA16(kf, qf[ks], s2[ni]);
            }
        }

        // mask (per kv = ni*16 + lg*4 + r)
        const int* mrow = mask + b * Sseq + t0;
        #pragma unroll
        for (int ni = 0; ni < 4; ++ni) {
            int4 mv = *(const int4*)&mrow[ni * 16 + lg * 4];
            if (mv.x == 0) s2[ni][0] = -1e9f;
            if (mv.y == 0) s2[ni][1] = -1e9f;
            if (mv.z == 0) s2[ni][2] = -1e9f;
            if (mv.w == 0) s2[ni][3] = -1e9f;
        }

        // row max: 16 lane-local values + 2 shfl_xor across redundant lanes
        float pmax = fmaxf(fmaxf(s2[0][0], s2[0][1]), fmaxf(s2[0][2], s2[0][3]));
        #pragma unroll
        for (int ni = 1; ni < 4; ++ni)
            pmax = fmaxf(pmax,
                   fmaxf(fmaxf(s2[ni][0], s2[ni][1]), fmaxf(s2[ni][2], s2[ni][3])));
        pmax = fmaxf(pmax, __shfl_xor(pmax, 16));
        pmax = fmaxf(pmax, __shfl_xor(pmax, 32));

        // T13 defer-max: rescale only when max grew by > 8 (log2 units)
        if (__any(pmax > m_i + 8.0f)) {
            float mnew = fmaxf(m_i, pmax);
            float al = exp2f(m_i - mnew);     // for q = w*16 + lr
            m_i = mnew;
            l_i *= al;
            // fetch alpha for oacc rows q = w*16 + lg*4 + r (lane lg*4+r has it)
            #pragma unroll
            for (int r = 0; r < 4; ++r) {
                float alr = __shfl(al, lg * 4 + r);
                #pragma unroll
                for (int ni = 0; ni < 4; ++ni) oacc[ni][r] *= alr;
            }
        }

        // p = exp2(s - m), bounded by 2^8; write back to Ps[q][kv]
        float rsum = 0.f;
        #pragma unroll
        for (int ni = 0; ni < 4; ++ni) {
            #pragma unroll
            for (int r = 0; r < 4; ++r) {
                float p = exp2f(s2[ni][r] - m_i);
                Ps[w][lr][ni * 16 + lg * 4 + r] = (f16)p;
                rsum += p;
            }
        }
        rsum += __shfl_xor(rsum, 16);
        rsum += __shfl_xor(rsum, 32);
        l_i += rsum;

        // PV: O += P @ V  (A-frag row=lr from Ps, B-frag from Vts)
        #pragma unroll
        for (int ks = 0; ks < 2; ++ks) {
            f16x8 pf = *(const f16x8*)&Ps[w][lr][ks * 32 + lg * 8];
            #pragma unroll
            for (int ni = 0; ni < 4; ++ni) {
                int row = ni * 16 + lr;
                f16x8 vf = *(const f16x8*)
                    &Vts[row * 64 + ((((ks << 2) | lg) ^ (row & 7)) << 3)];
                oacc[ni] = MFMA16(pf, vf, oacc[ni]);
            }
        }
        __syncthreads();
    }

    // normalize (1/l for rows q=lg*4+r fetched from lane lg*4+r), store
    float invl = 1.0f / l_i;
    size_t rbase = (size_t)b * Sseq + q0 + w * 16;
    #pragma unroll
    for (int r = 0; r < 4; ++r) {
        float invr = __shfl(invl, lg * 4 + r);
        #pragma unroll
        for (int ni = 0; ni < 4; ++ni)
            o[(rbase + lg * 4 + r) * Dm + h * 64 + ni * 16 + lr] =
                (f16)(oacc[ni][r] * invr);
    }
}

// ---------------------------------------------------------------------------
// Buffer plan (ws = 32M f16 = 64MB; d_out doubles as scratch):
//   ws f16 [0,3M):    wcatT (wq*QS | wk | wv, each [1024][1024])
//   ws f16 [3M,4M):   woT
//   ws f16 [4M,6M):   w1T   [2048][1024]
//   ws f16 [6M,8M):   w2T   [1024][2048]
//   ws f16 [8M,16M):  xn -> ob -> an
//   ws f16 [16M,32M): qh,kh -> h1
//   d_out out-half:   vh (8M f16) + vth (8M f16) -> final out (fp32)
//   d_out attn-half:  bcat fp32[3072] (dead at step 5) -> attn (output #2)
// ---------------------------------------------------------------------------
extern "C" void kernel_launch(void* const* d_in, const int* in_sizes, int n_in,
                              void* d_out, int out_size, void* d_ws, size_t ws_size,
                              hipStream_t stream)
{
    const float* x     = (const float*)d_in[0];
    const int*   mask  = (const int*)  d_in[1];
    const float* wq    = (const float*)d_in[2];
    const float* bq    = (const float*)d_in[3];
    const float* wk    = (const float*)d_in[4];
    const float* bk    = (const float*)d_in[5];
    const float* wv    = (const float*)d_in[6];
    const float* bv    = (const float*)d_in[7];
    const float* wo    = (const float*)d_in[8];
    const float* bo    = (const float*)d_in[9];
    const float* w1    = (const float*)d_in[10];
    const float* b1    = (const float*)d_in[11];
    const float* w2    = (const float*)d_in[12];
    const float* b2    = (const float*)d_in[13];
    const float* g1    = (const float*)d_in[14];
    const float* beta1 = (const float*)d_in[15];
    const float* g2    = (const float*)d_in[16];
    const float* beta2 = (const float*)d_in[17];

    float* out  = (float*)d_out;
    float* attn = out + EIGHT_M;

    const size_t M1 = 1024 * 1024;
    f16* ws16 = (f16*)d_ws;
    f16* wcatT = ws16;               // 3M
    f16* woT   = ws16 + 3 * M1;
    f16* w1T   = ws16 + 4 * M1;      // [2048][1024]
    f16* w2T   = ws16 + 6 * M1;      // [1024][2048]
    f16* xn    = ws16 + 8 * M1;      // 8M
    f16* ob    = xn;                 // alias (xn dead after QKV)
    f16* an    = xn;                 // alias (ob dead after O-proj)
    f16* qh    = ws16 + 16 * M1;     // 8M
    f16* kh    = ws16 + 24 * M1;     // 8M
    f16* h1    = qh;                 // 16M (q,k dead)
    f16* vh    = (f16*)d_out;        // out-half scratch
    f16* vth   = vh + 8 * M1;
    float* bcat = attn;              // 3072 fp32, dead before attn written

    dim3 tb256(256);

    // 0. weight prep
    transcast_k<<<dim3(32, 32), tb256, 0, stream>>>(wq, wcatT,          1024, 1024, QSCALE);
    transcast_k<<<dim3(32, 32), tb256, 0, stream>>>(wk, wcatT + 1 * M1, 1024, 1024, 1.0f);
    transcast_k<<<dim3(32, 32), tb256, 0, stream>>>(wv, wcatT + 2 * M1, 1024, 1024, 1.0f);
    transcast_k<<<dim3(32, 32), tb256, 0, stream>>>(wo, woT,            1024, 1024, 1.0f);
    transcast_k<<<dim3(64, 32), tb256, 0, stream>>>(w1, w1T,            1024, 2048, 1.0f);
    transcast_k<<<dim3(32, 64), tb256, 0, stream>>>(w2, w2T,            2048, 1024, 1.0f);
    biascat_k<<<12, tb256, 0, stream>>>(bq, bk, bv, bcat);

    // 1. LN1
    ln_k<<<ROWS, tb256, 0, stream>>>(x, g1, beta1, xn);

    // 2. fused QKV projection (head layout f16; Q pre-scaled by QSCALE)
    gemm4_k<0><<<dim3(3072 / 128, ROWS / 128), tb256, 0, stream>>>(
        xn, wcatT, bcat, qh, kh, vh, nullptr, ROWS, 3072, Dm);

    // 3. V -> V^T per head
    vtrans_k<<<dim3(16, 128), tb256, 0, stream>>>(vh, vth);

    // 4. flash attention -> ob row-major f16
    attn_k<<<dim3(16, 128), tb256, 0, stream>>>(qh, kh, vth, mask, ob);

    // 5. O projection + residual -> attn (fp32, output #2)
    gemm4_k<1><<<dim3(1024 / 128, ROWS / 128), tb256, 0, stream>>>(
        ob, woT, bo, attn, nullptr, nullptr, x, ROWS, Dm, Dm);

    // 6. LN2 -> an f16
    ln_k<<<ROWS, tb256, 0, stream>>>(attn, g2, beta2, an);

    // 7. FFN1: relu(an @ w1 + b1) -> h1 f16
    gemm4_k<2><<<dim3(2048 / 128, ROWS / 128), tb256, 0, stream>>>(
        an, w1T, b1, h1, nullptr, nullptr, nullptr, ROWS, DFF, Dm);

    // 8. FFN2: attn + h1 @ w2 + b2 -> out (fp32, output #1)
    gemm4_k<1><<<dim3(1024 / 128, ROWS / 128), tb256, 0, stream>>>(
        h1, w2T, b2, out, nullptr, nullptr, attn, ROWS, Dm, DFF);
}

// Round 13
// 550.452 us; speedup vs baseline: 1.1038x; 1.0235x over previous
//
#include <hip/hip_runtime.h>
#include <cstddef>
#include <cstdint>

// Problem constants
#define Bsz 8
#define Sseq 1024
#define Dm 1024
#define Hh 16
#define DH 64
#define DFF 2048
#define ROWS (Bsz*Sseq)            // 8192
#define EIGHT_M (8u*1024u*1024u)   // 8388608

#define QSCALE 0.180336880f        // 0.125 * log2(e) — folds softmax base-2

typedef _Float16 f16;
typedef _Float16 f16x8 __attribute__((ext_vector_type(8)));
typedef _Float16 f16x4 __attribute__((ext_vector_type(4)));
typedef float    f32x4 __attribute__((ext_vector_type(4)));

#define MFMA16(a,b,c) __builtin_amdgcn_mfma_f32_16x16x32_f16(a, b, c, 0, 0, 0)

// global->LDS direct copy, 16B per lane. LDS dst wave-uniform base; HW writes
// dst + lane*16. Global src per-lane.
__device__ __forceinline__ void glds16(const void* g, void* l) {
    __builtin_amdgcn_global_load_lds(
        (const __attribute__((address_space(1))) unsigned int*)g,
        (__attribute__((address_space(3))) unsigned int*)l, 16, 0, 0);
}

// ---------------------------------------------------------------------------
// LayerNorm (fp32 in, f16 out). One block per row of 1024.
// ---------------------------------------------------------------------------
__global__ __launch_bounds__(256) void ln_k(const float* __restrict__ x,
                                            const float* __restrict__ gain,
                                            const float* __restrict__ beta,
                                            f16* __restrict__ y)
{
    int row = blockIdx.x;
    const float* xr = x + (size_t)row * Dm;
    int tid = threadIdx.x;

    float4 v = *(const float4*)&xr[tid * 4];
    float s  = v.x + v.y + v.z + v.w;
    float sq = v.x*v.x + v.y*v.y + v.z*v.z + v.w*v.w;

    #pragma unroll
    for (int off = 32; off > 0; off >>= 1) {
        s  += __shfl_down(s,  off);
        sq += __shfl_down(sq, off);
    }
    __shared__ float ss[4], ssq[4];
    int w = tid >> 6, ln = tid & 63;
    if (ln == 0) { ss[w] = s; ssq[w] = sq; }
    __syncthreads();
    float S  = ss[0] + ss[1] + ss[2] + ss[3];
    float SQ = ssq[0] + ssq[1] + ssq[2] + ssq[3];

    float mean = S * (1.0f / 1024.0f);
    float var  = (SQ - 1024.0f * mean * mean) * (1.0f / 1023.0f);
    var = fmaxf(var, 0.0f);
    float inv = 1.0f / (sqrtf(var) + 1e-6f);

    float4 gv = *(const float4*)&gain[tid * 4];
    float4 bv = *(const float4*)&beta[tid * 4];
    f16x4 o;
    o[0] = (f16)(gv.x * inv * (v.x - mean) + bv.x);
    o[1] = (f16)(gv.y * inv * (v.y - mean) + bv.y);
    o[2] = (f16)(gv.z * inv * (v.z - mean) + bv.z);
    o[3] = (f16)(gv.w * inv * (v.w - mean) + bv.w);
    *(f16x4*)&y[(size_t)row * Dm + tid * 4] = o;
}

// ---------------------------------------------------------------------------
// Weight transpose+cast+scale: src fp32 [K][N] -> dst f16 [N][K]
// ---------------------------------------------------------------------------
__global__ __launch_bounds__(256) void transcast_k(const float* __restrict__ src,
                                                   f16* __restrict__ dst,
                                                   int K, int N, float scale)
{
    __shared__ float t[32][33];
    int n0 = blockIdx.x * 32, k0 = blockIdx.y * 32;
    int tx = threadIdx.x & 31, ty = threadIdx.x >> 5;   // ty 0..7
    #pragma unroll
    for (int i = 0; i < 4; ++i)
        t[ty + 8*i][tx] = src[(size_t)(k0 + ty + 8*i) * N + n0 + tx];
    __syncthreads();
    #pragma unroll
    for (int i = 0; i < 4; ++i)
        dst[(size_t)(n0 + ty + 8*i) * K + k0 + tx] = (f16)(t[tx][ty + 8*i] * scale);
}

// ---------------------------------------------------------------------------
// Bias concat: bcat[0:1024)=bq*QSCALE, [1024:2048)=bk, [2048:3072)=bv
// ---------------------------------------------------------------------------
__global__ __launch_bounds__(256) void biascat_k(const float* __restrict__ bq,
                                                 const float* __restrict__ bk,
                                                 const float* __restrict__ bv,
                                                 float* __restrict__ bcat)
{
    int i = blockIdx.x * 256 + threadIdx.x;   // 0..3071
    float v;
    if (i < 1024)       v = bq[i] * QSCALE;
    else if (i < 2048)  v = bk[i - 1024];
    else                v = bv[i - 2048];
    bcat[i] = v;
}

// ---------------------------------------------------------------------------
// V head-layout [bh][s][d] -> V^T [bh][d][s]  (f16)
// ---------------------------------------------------------------------------
__global__ __launch_bounds__(256) void vtrans_k(const f16* __restrict__ v,
                                                f16* __restrict__ vt)
{
    int bh = blockIdx.y;
    int s0 = blockIdx.x * 64;
    __shared__ f16 t[64][72];
    int tid = threadIdx.x;
    int sl = tid >> 2, dq = (tid & 3) * 16;
    const f16* src = v + ((size_t)bh * Sseq + s0 + sl) * DH + dq;
    *(f16x8*)&t[sl][dq]     = *(const f16x8*)&src[0];
    *(f16x8*)&t[sl][dq + 8] = *(const f16x8*)&src[8];
    __syncthreads();
    int d = tid >> 2, sq = (tid & 3) * 16;
    f16 buf[16];
    #pragma unroll
    for (int i = 0; i < 16; ++i) buf[i] = t[sq + i][d];
    f16* dst = vt + ((size_t)bh * DH + d) * Sseq + s0 + sq;
    *(f16x8*)&dst[0] = *(f16x8*)&buf[0];
    *(f16x8*)&dst[8] = *(f16x8*)&buf[8];
}

// ---------------------------------------------------------------------------
// gemm5: gemm4 with DEPTH-3 prefetch (4-slot ring) + XCD swizzle.
//   R12 post-mortem: gemm4's depth-2 ring self-limits at T = HBMlat/2 ~ 500cyc
//   (MfmaUtil 17.7%). Fix: slot hh staged at iter hh-3, waited at iter hh
//   -> lead = 3T; plus XCD swizzle turns most loads into L2 hits (~250cyc),
//   which a ~400cyc lead fully covers.
//   BM=BN=128, BK=32/slot, 256 threads = 4 waves (2M x 2N), per-wave C 64x64.
//   LDS: As[4][4096]+Bs[4][4096] f16 = 64KB -> 2 blocks/CU.
//   u-major chunk layout (chunk c = u*128+row, addr c*16B): quarter-wave
//   ds_read_b128 = 256B contiguous -> conflict-free (R8/R12: 0 conflicts);
//   glds dest linear -> rule-21 by construction.
//   Per iter hh: vmcnt(8) [retire slot hh's 4 loads; hh+1,hh+2's 8 stay in
//   flight] -> barrier [publish] -> STAGE slot hh+3 [prev occupant hh-1 was
//   consumed before this barrier] -> ds_read A(4)+B(4) -> 16 MFMA (setprio).
//   Drain: vmcnt 8 / 4 / 0 at rem >=2 / 1 / 0.
// EPI 0: fused QKV -> head-layout f16 (C0/C1/C2 by n0>>10)
// EPI 1: fp32 out + fp32 residual
// EPI 2: relu -> f16 row-major
// ---------------------------------------------------------------------------
template<int EPI>
__global__ __launch_bounds__(256) void gemm5_k(const f16* __restrict__ A,
                                               const f16* __restrict__ Bt,
                                               const float* __restrict__ bias,
                                               void* __restrict__ C0,
                                               void* __restrict__ C1,
                                               void* __restrict__ C2,
                                               const float* __restrict__ res,
                                               int M, int N, int K)
{
    __shared__ f16 As[4][4096];   // [slot][512 chunks * 8 f16] = 8KB/slot
    __shared__ f16 Bs[4][4096];

    const int tid  = threadIdx.x;
    const int lane = tid & 63, w = tid >> 6;     // 4 waves
    const int wr = w >> 1, wc = w & 1;           // 2M x 2N
    const int lr = lane & 15, lg = lane >> 4;

    // XCD-aware bijective swizzle (all grids here have nwg % 8 == 0):
    // consecutive dispatch ids land on the same XCD in chunks -> A/W panel
    // reuse hits that XCD's L2.
    const int gx  = gridDim.x;
    const int nwg = gx * gridDim.y;
    int lin = blockIdx.y * gx + blockIdx.x;
    int swz = (lin & 7) * (nwg >> 3) + (lin >> 3);
    const int m0 = (swz / gx) * 128, n0 = (swz % gx) * 128;

    // staging: 512 chunks per slot; rounds r=0,1: chunk c = r*256 + w*64 + lane
    // chunk c -> row (c&127), u (c>>7); src elem = row*K + kbase + u*8
    const int c0 = w * 64 + lane;
    const int c1 = c0 + 256;
    const f16* srcA0 = A  + (size_t)(m0 + (c0 & 127)) * K + ((c0 >> 7) << 3);
    const f16* srcA1 = A  + (size_t)(m0 + (c1 & 127)) * K + ((c1 >> 7) << 3);
    const f16* srcB0 = Bt + (size_t)(n0 + (c0 & 127)) * K + ((c0 >> 7) << 3);
    const f16* srcB1 = Bt + (size_t)(n0 + (c1 & 127)) * K + ((c1 >> 7) << 3);
    const int dst0 = (w * 64) * 8;            // wave-uniform f16 offsets
    const int dst1 = (256 + w * 64) * 8;

    f32x4 acc[4][4];
    #pragma unroll
    for (int i = 0; i < 4; ++i)
        #pragma unroll
        for (int j = 0; j < 4; ++j)
            acc[i][j] = (f32x4){0.f, 0.f, 0.f, 0.f};

    int aoff[4], boff[4];
    #pragma unroll
    for (int mi = 0; mi < 4; ++mi)
        aoff[mi] = (lg * 128 + wr * 64 + mi * 16 + lr) * 8;
    #pragma unroll
    for (int nf = 0; nf < 4; ++nf)
        boff[nf] = (lg * 128 + wc * 64 + nf * 16 + lr) * 8;

    #define STAGE(sl_, kb_) do {                                         \
        glds16(srcA0 + (kb_), &As[sl_][dst0]);                           \
        glds16(srcA1 + (kb_), &As[sl_][dst1]);                           \
        glds16(srcB0 + (kb_), &Bs[sl_][dst0]);                           \
        glds16(srcB1 + (kb_), &Bs[sl_][dst1]);                           \
    } while (0)

    #define FENCE() asm volatile("" ::: "memory")

    // prologue: stage halves 0,1,2 into slots 0,1,2 (12 loads in flight)
    STAGE(0, 0);
    STAGE(1, 32);
    STAGE(2, 64);
    FENCE();

    const int NH = K >> 5;      // number of 32-k halves (>= 32 here)
    for (int hh = 0; hh < NH; ++hh) {
        const int sl = hh & 3;
        const int rem = NH - 1 - hh;
        // retire slot hh's own 4 loads; keep hh+1, hh+2's in flight
        if (rem >= 2) {
            asm volatile("s_waitcnt vmcnt(8)" ::: "memory");
        } else if (rem == 1) {
            asm volatile("s_waitcnt vmcnt(4)" ::: "memory");
        } else {
            asm volatile("s_waitcnt vmcnt(0)" ::: "memory");
        }
        __builtin_amdgcn_s_barrier();   // slot hh fully landed + published;
        FENCE();                        // slot (hh+3)%4's old data consumed
        if (hh + 3 < NH) STAGE((hh + 3) & 3, (hh + 3) * 32);

        // sub-phase 0: A-frags (reused below) + B lower half
        f16x8 a0 = *(const f16x8*)&As[sl][aoff[0]];
        f16x8 a1 = *(const f16x8*)&As[sl][aoff[1]];
        f16x8 a2 = *(const f16x8*)&As[sl][aoff[2]];
        f16x8 a3 = *(const f16x8*)&As[sl][aoff[3]];
        f16x8 b0 = *(const f16x8*)&Bs[sl][boff[0]];
        f16x8 b1 = *(const f16x8*)&Bs[sl][boff[1]];
        __builtin_amdgcn_s_setprio(1);
        acc[0][0] = MFMA16(a0, b0, acc[0][0]);
        acc[0][1] = MFMA16(a0, b1, acc[0][1]);
        acc[1][0] = MFMA16(a1, b0, acc[1][0]);
        acc[1][1] = MFMA16(a1, b1, acc[1][1]);
        acc[2][0] = MFMA16(a2, b0, acc[2][0]);
        acc[2][1] = MFMA16(a2, b1, acc[2][1]);
        acc[3][0] = MFMA16(a3, b0, acc[3][0]);
        acc[3][1] = MFMA16(a3, b1, acc[3][1]);
        __builtin_amdgcn_s_setprio(0);

        // sub-phase 1: B upper half (A reused from registers)
        f16x8 b2 = *(const f16x8*)&Bs[sl][boff[2]];
        f16x8 b3 = *(const f16x8*)&Bs[sl][boff[3]];
        __builtin_amdgcn_s_setprio(1);
        acc[0][2] = MFMA16(a0, b2, acc[0][2]);
        acc[0][3] = MFMA16(a0, b3, acc[0][3]);
        acc[1][2] = MFMA16(a1, b2, acc[1][2]);
        acc[1][3] = MFMA16(a1, b3, acc[1][3]);
        acc[2][2] = MFMA16(a2, b2, acc[2][2]);
        acc[2][3] = MFMA16(a2, b3, acc[2][3]);
        acc[3][2] = MFMA16(a3, b2, acc[3][2]);
        acc[3][3] = MFMA16(a3, b3, acc[3][3]);
        __builtin_amdgcn_s_setprio(0);

        FENCE();
    }
    #undef STAGE
    #undef FENCE

    // epilogue: lane holds C[row = lg*4+r][col = lr] per 16x16 frag
    if constexpr (EPI == 0) {
        int seg = n0 >> 10;                 // uniform per block
        f16* dst = (seg == 0) ? (f16*)C0 : ((seg == 1) ? (f16*)C1 : (f16*)C2);
        int nn0 = n0 & 1023;
        #pragma unroll
        for (int mi = 0; mi < 4; ++mi)
            #pragma unroll
            for (int r = 0; r < 4; ++r) {
                int gm = m0 + wr * 64 + mi * 16 + lg * 4 + r;
                int b = gm >> 10, s = gm & 1023;
                #pragma unroll
                for (int nf = 0; nf < 4; ++nf) {
                    int n = nn0 + wc * 64 + nf * 16 + lr;
                    int h = n >> 6, d = n & 63;
                    float v = acc[mi][nf][r] + bias[n0 + wc * 64 + nf * 16 + lr];
                    dst[(((size_t)(b * 16 + h) * 1024 + s) << 6) + d] = (f16)v;
                }
            }
    } else {
        #pragma unroll
        for (int mi = 0; mi < 4; ++mi)
            #pragma unroll
            for (int r = 0; r < 4; ++r) {
                int gm = m0 + wr * 64 + mi * 16 + lg * 4 + r;
                #pragma unroll
                for (int nf = 0; nf < 4; ++nf) {
                    int gn = n0 + wc * 64 + nf * 16 + lr;
                    float v = acc[mi][nf][r] + bias[gn];
                    if constexpr (EPI == 1) {
                        ((float*)C0)[(size_t)gm * N + gn] =
                            v + res[(size_t)gm * N + gn];
                    } else {
                        ((f16*)C0)[(size_t)gm * N + gn] = (f16)fmaxf(v, 0.f);
                    }
                }
            }
    }
}

// ---------------------------------------------------------------------------
// MFMA flash attention with SWAPPED QK^T -> lane-local softmax (unchanged
// from round 8/12, which passed at absmax 0.03125).
// ---------------------------------------------------------------------------
__global__ __launch_bounds__(256) void attn_k(const f16* __restrict__ q,
                                              const f16* __restrict__ k,
                                              const f16* __restrict__ vt,
                                              const int* __restrict__ mask,
                                              f16* __restrict__ o)
{
    int bh = blockIdx.y;          // 0..127
    int b  = bh >> 4, h = bh & 15;
    int q0 = blockIdx.x * 64;

    const f16* Qb = q  + (size_t)bh * (Sseq * DH);   // [s][d]
    const f16* Kb = k  + (size_t)bh * (Sseq * DH);   // [s][d]
    const f16* Vb = vt + (size_t)bh * (DH * Sseq);   // [d][s]

    __shared__ f16 Ks[64 * 64];      // [kv][d] swizzled
    __shared__ f16 Vts[64 * 64];     // [d][kv] swizzled
    __shared__ f16 Ps[4][16][72];    // per-wave P[q within tile][kv], padded

    int tid  = threadIdx.x;
    int lane = tid & 63, w = tid >> 6;
    int lr = lane & 15, lg = lane >> 4;

    f16x8 qf[2];
    {
        const f16* qr = Qb + (size_t)(q0 + w * 16 + lr) * DH + lg * 8;
        qf[0] = *(const f16x8*)&qr[0];
        qf[1] = *(const f16x8*)&qr[32];
    }

    f32x4 oacc[4];
    #pragma unroll
    for (int ni = 0; ni < 4; ++ni) oacc[ni] = (f32x4){0.f, 0.f, 0.f, 0.f};
    float m_i = -1e30f, l_i = 0.f;        // state for q = w*16 + lr

    int srow8 = lane >> 3;        // 0..7 row-in-chunk
    int sc16  = lane & 7;         // 16B unit in row

    for (int t0 = 0; t0 < Sseq; t0 += 64) {
        #pragma unroll
        for (int c = 0; c < 2; ++c) {
            int ch  = 2 * w + c;
            int row = ch * 8 + srow8;
            int cs  = sc16 ^ (row & 7);   // inverse-swizzled source unit
            glds16(Kb + (size_t)(t0 + row) * DH + cs * 8,  Ks  + ch * 512);
            glds16(Vb + (size_t)row * Sseq + t0 + cs * 8,  Vts + ch * 512);
        }
        __syncthreads();

        // S^T = K @ Q^T : s2[ni][r] = S[q=w*16+lr][kv=t0+ni*16+lg*4+r]
        f32x4 s2[4];
        #pragma unroll
        for (int ni = 0; ni < 4; ++ni) s2[ni] = (f32x4){0.f, 0.f, 0.f, 0.f};
        #pragma unroll
        for (int ks = 0; ks < 2; ++ks) {
            #pragma unroll
            for (int ni = 0; ni < 4; ++ni) {
                int row = ni * 16 + lr;
                f16x8 kf = *(const f16x8*)
                    &Ks[row * 64 + ((((ks << 2) | lg) ^ (row & 7)) << 3)];
                s2[ni] = MFMA16(kf, qf[ks], s2[ni]);
            }
        }

        // mask (per kv = ni*16 + lg*4 + r)
        const int* mrow = mask + b * Sseq + t0;
        #pragma unroll
        for (int ni = 0; ni < 4; ++ni) {
            int4 mv = *(const int4*)&mrow[ni * 16 + lg * 4];
            if (mv.x == 0) s2[ni][0] = -1e9f;
            if (mv.y == 0) s2[ni][1] = -1e9f;
            if (mv.z == 0) s2[ni][2] = -1e9f;
            if (mv.w == 0) s2[ni][3] = -1e9f;
        }

        // row max: 16 lane-local values + 2 shfl_xor across redundant lanes
        float pmax = fmaxf(fmaxf(s2[0][0], s2[0][1]), fmaxf(s2[0][2], s2[0][3]));
        #pragma unroll
        for (int ni = 1; ni < 4; ++ni)
            pmax = fmaxf(pmax,
                   fmaxf(fmaxf(s2[ni][0], s2[ni][1]), fmaxf(s2[ni][2], s2[ni][3])));
        pmax = fmaxf(pmax, __shfl_xor(pmax, 16));
        pmax = fmaxf(pmax, __shfl_xor(pmax, 32));

        // T13 defer-max: rescale only when max grew by > 8 (log2 units)
        if (__any(pmax > m_i + 8.0f)) {
            float mnew = fmaxf(m_i, pmax);
            float al = exp2f(m_i - mnew);     // for q = w*16 + lr
            m_i = mnew;
            l_i *= al;
            // fetch alpha for oacc rows q = w*16 + lg*4 + r (lane lg*4+r has it)
            #pragma unroll
            for (int r = 0; r < 4; ++r) {
                float alr = __shfl(al, lg * 4 + r);
                #pragma unroll
                for (int ni = 0; ni < 4; ++ni) oacc[ni][r] *= alr;
            }
        }

        // p = exp2(s - m), bounded by 2^8; write back to Ps[q][kv]
        float rsum = 0.f;
        #pragma unroll
        for (int ni = 0; ni < 4; ++ni) {
            #pragma unroll
            for (int r = 0; r < 4; ++r) {
                float p = exp2f(s2[ni][r] - m_i);
                Ps[w][lr][ni * 16 + lg * 4 + r] = (f16)p;
                rsum += p;
            }
        }
        rsum += __shfl_xor(rsum, 16);
        rsum += __shfl_xor(rsum, 32);
        l_i += rsum;

        // PV: O += P @ V  (A-frag row=lr from Ps, B-frag from Vts)
        #pragma unroll
        for (int ks = 0; ks < 2; ++ks) {
            f16x8 pf = *(const f16x8*)&Ps[w][lr][ks * 32 + lg * 8];
            #pragma unroll
            for (int ni = 0; ni < 4; ++ni) {
                int row = ni * 16 + lr;
                f16x8 vf = *(const f16x8*)
                    &Vts[row * 64 + ((((ks << 2) | lg) ^ (row & 7)) << 3)];
                oacc[ni] = MFMA16(pf, vf, oacc[ni]);
            }
        }
        __syncthreads();
    }

    // normalize (1/l for rows q=lg*4+r fetched from lane lg*4+r), store
    float invl = 1.0f / l_i;
    size_t rbase = (size_t)b * Sseq + q0 + w * 16;
    #pragma unroll
    for (int r = 0; r < 4; ++r) {
        float invr = __shfl(invl, lg * 4 + r);
        #pragma unroll
        for (int ni = 0; ni < 4; ++ni)
            o[(rbase + lg * 4 + r) * Dm + h * 64 + ni * 16 + lr] =
                (f16)(oacc[ni][r] * invr);
    }
}

// ---------------------------------------------------------------------------
// Buffer plan (ws = 32M f16 = 64MB; d_out doubles as scratch):
//   ws f16 [0,3M):    wcatT (wq*QS | wk | wv, each [1024][1024])
//   ws f16 [3M,4M):   woT
//   ws f16 [4M,6M):   w1T   [2048][1024]
//   ws f16 [6M,8M):   w2T   [1024][2048]
//   ws f16 [8M,16M):  xn -> ob -> an
//   ws f16 [16M,32M): qh,kh -> h1
//   d_out out-half:   vh (8M f16) + vth (8M f16) -> final out (fp32)
//   d_out attn-half:  bcat fp32[3072] (dead at step 5) -> attn (output #2)
// ---------------------------------------------------------------------------
extern "C" void kernel_launch(void* const* d_in, const int* in_sizes, int n_in,
                              void* d_out, int out_size, void* d_ws, size_t ws_size,
                              hipStream_t stream)
{
    const float* x     = (const float*)d_in[0];
    const int*   mask  = (const int*)  d_in[1];
    const float* wq    = (const float*)d_in[2];
    const float* bq    = (const float*)d_in[3];
    const float* wk    = (const float*)d_in[4];
    const float* bk    = (const float*)d_in[5];
    const float* wv    = (const float*)d_in[6];
    const float* bv    = (const float*)d_in[7];
    const float* wo    = (const float*)d_in[8];
    const float* bo    = (const float*)d_in[9];
    const float* w1    = (const float*)d_in[10];
    const float* b1    = (const float*)d_in[11];
    const float* w2    = (const float*)d_in[12];
    const float* b2    = (const float*)d_in[13];
    const float* g1    = (const float*)d_in[14];
    const float* beta1 = (const float*)d_in[15];
    const float* g2    = (const float*)d_in[16];
    const float* beta2 = (const float*)d_in[17];

    float* out  = (float*)d_out;
    float* attn = out + EIGHT_M;

    const size_t M1 = 1024 * 1024;
    f16* ws16 = (f16*)d_ws;
    f16* wcatT = ws16;               // 3M
    f16* woT   = ws16 + 3 * M1;
    f16* w1T   = ws16 + 4 * M1;      // [2048][1024]
    f16* w2T   = ws16 + 6 * M1;      // [1024][2048]
    f16* xn    = ws16 + 8 * M1;      // 8M
    f16* ob    = xn;                 // alias (xn dead after QKV)
    f16* an    = xn;                 // alias (ob dead after O-proj)
    f16* qh    = ws16 + 16 * M1;     // 8M
    f16* kh    = ws16 + 24 * M1;     // 8M
    f16* h1    = qh;                 // 16M (q,k dead)
    f16* vh    = (f16*)d_out;        // out-half scratch
    f16* vth   = vh + 8 * M1;
    float* bcat = attn;              // 3072 fp32, dead before attn written

    dim3 tb256(256);

    // 0. weight prep
    transcast_k<<<dim3(32, 32), tb256, 0, stream>>>(wq, wcatT,          1024, 1024, QSCALE);
    transcast_k<<<dim3(32, 32), tb256, 0, stream>>>(wk, wcatT + 1 * M1, 1024, 1024, 1.0f);
    transcast_k<<<dim3(32, 32), tb256, 0, stream>>>(wv, wcatT + 2 * M1, 1024, 1024, 1.0f);
    transcast_k<<<dim3(32, 32), tb256, 0, stream>>>(wo, woT,            1024, 1024, 1.0f);
    transcast_k<<<dim3(64, 32), tb256, 0, stream>>>(w1, w1T,            1024, 2048, 1.0f);
    transcast_k<<<dim3(32, 64), tb256, 0, stream>>>(w2, w2T,            2048, 1024, 1.0f);
    biascat_k<<<12, tb256, 0, stream>>>(bq, bk, bv, bcat);

    // 1. LN1
    ln_k<<<ROWS, tb256, 0, stream>>>(x, g1, beta1, xn);

    // 2. fused QKV projection (head layout f16; Q pre-scaled by QSCALE)
    gemm5_k<0><<<dim3(3072 / 128, ROWS / 128), tb256, 0, stream>>>(
        xn, wcatT, bcat, qh, kh, vh, nullptr, ROWS, 3072, Dm);

    // 3. V -> V^T per head
    vtrans_k<<<dim3(16, 128), tb256, 0, stream>>>(vh, vth);

    // 4. flash attention -> ob row-major f16
    attn_k<<<dim3(16, 128), tb256, 0, stream>>>(qh, kh, vth, mask, ob);

    // 5. O projection + residual -> attn (fp32, output #2)
    gemm5_k<1><<<dim3(1024 / 128, ROWS / 128), tb256, 0, stream>>>(
        ob, woT, bo, attn, nullptr, nullptr, x, ROWS, Dm, Dm);

    // 6. LN2 -> an f16
    ln_k<<<ROWS, tb256, 0, stream>>>(attn, g2, beta2, an);

    // 7. FFN1: relu(an @ w1 + b1) -> h1 f16
    gemm5_k<2><<<dim3(2048 / 128, ROWS / 128), tb256, 0, stream>>>(
        an, w1T, b1, h1, nullptr, nullptr, nullptr, ROWS, DFF, Dm);

    // 8. FFN2: attn + h1 @ w2 + b2 -> out (fp32, output #1)
    gemm5_k<1><<<dim3(1024 / 128, ROWS / 128), tb256, 0, stream>>>(
        h1, w2T, b2, out, nullptr, nullptr, attn, ROWS, Dm, DFF);
}